// Round 8
// baseline (282.915 us; speedup 1.0000x reference)
//
#include <hip/hip_runtime.h>

#define TLEN 512
#define HID  64

typedef _Float16 half8 __attribute__((ext_vector_type(8)));
typedef float    f32x4 __attribute__((ext_vector_type(4)));

__device__ __forceinline__ float rcp_fast(float x) { return __builtin_amdgcn_rcpf(x); }
__device__ __forceinline__ float exp2_fast(float x) {
#if __has_builtin(__builtin_amdgcn_exp2f)
    return __builtin_amdgcn_exp2f(x);
#else
    float r; asm("v_exp_f32 %0, %1" : "=v"(r) : "v"(x)); return r;
#endif
}

// R8: 512 blocks x 8 waves (4 batch rows/block). 4096 waves = 4 waves/SIMD
// (2 independent blocks/CU) -- R7's counters showed ~390 cyc/SIMD-step of
// unhidden dependency-chain stall at 2 ctx; 4 ctx interleaves it.
// Wave w owns units [8w,8w+8) as 2 row-permuted A-tiles (select-of-2, was 4).
// waves_per_eu(4,4) forces VGPR<=128 so 4 waves/EU actually materialize.
// Activation in exp2 domain: log2e folded into wih/bias at setup.
// C/D layout col=lane&15 (batch b=c&3), row=(lane>>4)*4+reg = 4 gates of one
// unit in one lane's acc regs (row-permuted W_hh, validated R5-R7).
__global__ __launch_bounds__(512) __attribute__((amdgpu_waves_per_eu(4, 4)))
void lstm_mfma5(const float* __restrict__ x,
                const float* __restrict__ W_ih,
                const float* __restrict__ W_hh,
                const float* __restrict__ b_ih,
                const float* __restrict__ b_hh,
                const float* __restrict__ W_d,
                const float* __restrict__ b_d,
                float* __restrict__ out) {
    __shared__ __align__(16) float    xs[4][516];     // 4 x rows
    __shared__ __align__(16) _Float16 hbuf[2][4][72]; // ping-pong h

    const int tid = threadIdx.x;
    const int L   = tid & 63;
    const int w   = tid >> 6;        // wave 0..7, owns units [8w, 8w+8)
    const int r0  = blockIdx.x * 4;

    // ---- stage x rows (float4) ----
    for (int i = tid; i < 4 * 128; i += 512) {
        const int r = i >> 7, t4 = (i & 127) * 4;
        *(float4*)&xs[r][t4] = *(const float4*)&x[(size_t)(r0 + r) * TLEN + t4];
    }
    // ---- zero both h buffers (h0 = 0) ----
    for (int i = tid; i < 2 * 4 * 72; i += 512)
        ((_Float16*)hbuf)[i] = (_Float16)0.0f;

    // ---- resident A-frags: A[m][k], m=L&15, k=32q+(L>>4)*8+i ----
    // perm: tile tt -> unit 8w+4tt+(m>>2), gate m&3 (i,f,g,o)
    half8 af[2][2];
    {
        const int m = L & 15;
        const int g = m & 3;
        const int kb = (L >> 4) * 8;
#pragma unroll
        for (int tt = 0; tt < 2; ++tt) {
            const int uu = 8 * w + 4 * tt + (m >> 2);
            const float* row = &W_hh[(size_t)(g * HID + uu) * HID];
#pragma unroll
            for (int q = 0; q < 2; ++q) {
                const float* p = row + 32 * q + kb;
                half8 hf;
#pragma unroll
                for (int i = 0; i < 8; ++i) hf[i] = (_Float16)p[i];
                af[tt][q] = hf;
            }
        }
    }

    // ---- lane role: batch b, tile-select sel, unit u ----
    const int c   = L & 15;
    const int b   = c & 3;
    const int sel = (c >> 2) & 1;    // dup groups 0..3 -> tiles 0,1,0,1
    const int u   = 8 * w + 4 * sel + (L >> 4);

    // exp2-domain gate params: arg_i = -K*(d+pre) etc. K = log2(e)
    const float K = 1.44269504f;
    float wih[4], bias[4], dscl[4];
#pragma unroll
    for (int g = 0; g < 4; ++g) {
        const float s = (g == 2) ? 2.0f * K : -K;  // tanh gate: +2K, sigmoid: -K
        wih[g]  = s * W_ih[g * HID + u];
        bias[g] = s * (b_ih[g * HID + u] + b_hh[g * HID + u]);
        dscl[g] = s;
    }

    const float* xrow = &xs[b][0];
    const int koff = (L >> 4) * 8;
    const _Float16* h0r = &hbuf[0][b][0];
    _Float16*       h0w = &hbuf[0][b][0];
    const _Float16* h1r = &hbuf[1][b][0];
    _Float16*       h1w = &hbuf[1][b][0];
    const f32x4 zero = {0.0f, 0.0f, 0.0f, 0.0f};
    float cst = 0.0f;

    __syncthreads();

    auto step = [&](const _Float16* hin, _Float16* hout, float xt) {
        half8 b0 = *(const half8*)(hin + koff);        // broadcast-ish, cheap
        half8 b1 = *(const half8*)(hin + koff + 32);

        f32x4 d0 = __builtin_amdgcn_mfma_f32_16x16x32_f16(af[0][0], b0, zero, 0, 0, 0);
        f32x4 d1 = __builtin_amdgcn_mfma_f32_16x16x32_f16(af[1][0], b0, zero, 0, 0, 0);
        d0 = __builtin_amdgcn_mfma_f32_16x16x32_f16(af[0][1], b1, d0, 0, 0, 0);
        d1 = __builtin_amdgcn_mfma_f32_16x16x32_f16(af[1][1], b1, d1, 0, 0, 0);

        const f32x4 d = sel ? d1 : d0;   // 4 cndmask (lane-constant sel)

        // exp2-domain: e_g = exp2(s_g*d + s_g*(x*wih+bias))
        const float ei = exp2_fast(fmaf(d[0], dscl[0], fmaf(xt, wih[0], bias[0])));
        const float ef = exp2_fast(fmaf(d[1], dscl[1], fmaf(xt, wih[1], bias[1])));
        const float eg = exp2_fast(fmaf(d[2], dscl[2], fmaf(xt, wih[2], bias[2])));
        const float eo = exp2_fast(fmaf(d[3], dscl[3], fmaf(xt, wih[3], bias[3])));
        const float gi = rcp_fast(1.0f + ei);              // sigmoid
        const float gf = rcp_fast(1.0f + ef);
        const float gg = fmaf(-2.0f, rcp_fast(1.0f + eg), 1.0f);   // tanh
        const float go = rcp_fast(1.0f + eo);
        cst = fmaf(gf, cst, gi * gg);
        const float tc = fmaf(-2.0f, rcp_fast(1.0f + exp2_fast(2.0f * K * cst)), 1.0f);
        const float hv = go * tc;
        hout[u] = (_Float16)hv;   // dup lanes write same value to same addr (benign)
    };

    for (int t = 0; t < TLEN; t += 2) {
        step(h0r, h1w, xrow[t]);
        __syncthreads();
        step(h1r, h0w, xrow[t + 1]);
        __syncthreads();
    }

    // ---- epilogue: waves 0..3 reduce batch rows 0..3 (final h in hbuf[0]) ----
    if (w < 4) {
        float pv = (float)hbuf[0][w][L] * W_d[L];
#pragma unroll
        for (int off = 32; off > 0; off >>= 1)
            pv += __shfl_xor(pv, off, 64);
        if (L == 0)
            out[r0 + w] = pv + b_d[0];
    }
}

extern "C" void kernel_launch(void* const* d_in, const int* in_sizes, int n_in,
                              void* d_out, int out_size, void* d_ws, size_t ws_size,
                              hipStream_t stream) {
    const float* x    = (const float*)d_in[0];
    const float* W_ih = (const float*)d_in[1];
    const float* W_hh = (const float*)d_in[2];
    const float* b_ih = (const float*)d_in[3];
    const float* b_hh = (const float*)d_in[4];
    const float* W_d  = (const float*)d_in[5];
    const float* b_d  = (const float*)d_in[6];
    float* out = (float*)d_out;

    dim3 grid(512);    // 4 batch rows per block; 4096 waves = 4/SIMD
    dim3 block(512);   // 8 waves
    lstm_mfma5<<<grid, block, 0, stream>>>(x, W_ih, W_hh, b_ih, b_hh, W_d, b_d, out);
}

// Round 9
// 221.308 us; speedup vs baseline: 1.2784x; 1.2784x over previous
//
#include <hip/hip_runtime.h>

#define TLEN 512
#define HID  64

typedef _Float16 half8 __attribute__((ext_vector_type(8)));
typedef float    f32x4 __attribute__((ext_vector_type(4)));

__device__ __forceinline__ float rcp_fast(float x) { return __builtin_amdgcn_rcpf(x); }
__device__ __forceinline__ float exp2_fast(float x) {
#if __has_builtin(__builtin_amdgcn_exp2f)
    return __builtin_amdgcn_exp2f(x);
#else
    float r; asm("v_exp_f32 %0, %1" : "=v"(r) : "v"(x)); return r;
#endif
}

// R9: 256 blocks x 8 waves; block owns 8 REAL batch rows (16 MFMA cols = 8
// real, 2x dup -- R7 was 4x dup). Wave w owns units [8w,8w+8) as 2 row-
// permuted A-tiles -> 4 MFMA/step (chip MFMA halved vs R7). Exactly ONE
// activation per lane (R8's fatal 2x duplication removed): 2048 waves total
// = 2/SIMD, the occupancy floor for 1 act/lane. Select-of-2 (4 cndmask).
// exp2-domain activation (R8-validated): log2e folded into wih/bias.
// C/D: col=lane&15 (batch b=c&7), row=(lane>>4)*4+reg = 4 gates of unit
// 8w+4*tt+(lane>>4) in one lane's accs (perm validated R5-R8).
__global__ __launch_bounds__(512) __attribute__((amdgpu_waves_per_eu(2, 2)))
void lstm_mfma6(const float* __restrict__ x,
                const float* __restrict__ W_ih,
                const float* __restrict__ W_hh,
                const float* __restrict__ b_ih,
                const float* __restrict__ b_hh,
                const float* __restrict__ W_d,
                const float* __restrict__ b_d,
                float* __restrict__ out) {
    __shared__ __align__(16) float    xs[8][516];     // 8 x rows
    __shared__ __align__(16) _Float16 hbuf[2][8][72]; // ping-pong h

    const int tid = threadIdx.x;
    const int L   = tid & 63;
    const int w   = tid >> 6;        // wave 0..7, owns units [8w, 8w+8)
    const int r0  = blockIdx.x * 8;

    // ---- stage x rows (float4) ----
    for (int i = tid; i < 8 * 128; i += 512) {
        const int r = i >> 7, t4 = (i & 127) * 4;
        *(float4*)&xs[r][t4] = *(const float4*)&x[(size_t)(r0 + r) * TLEN + t4];
    }
    // ---- zero both h buffers (h0 = 0) ----
    for (int i = tid; i < 2 * 8 * 72; i += 512)
        ((_Float16*)hbuf)[i] = (_Float16)0.0f;

    // ---- resident A-frags: A[m][k], m=L&15, k=32q+(L>>4)*8+i ----
    // perm: tile tt -> unit 8w+4tt+(m>>2), gate m&3 (i,f,g,o)
    half8 af[2][2];
    {
        const int m = L & 15;
        const int g = m & 3;
        const int kb = (L >> 4) * 8;
#pragma unroll
        for (int tt = 0; tt < 2; ++tt) {
            const int uu = 8 * w + 4 * tt + (m >> 2);
            const float* row = &W_hh[(size_t)(g * HID + uu) * HID];
#pragma unroll
            for (int q = 0; q < 2; ++q) {
                const float* p = row + 32 * q + kb;
                half8 hf;
#pragma unroll
                for (int i = 0; i < 8; ++i) hf[i] = (_Float16)p[i];
                af[tt][q] = hf;
            }
        }
    }

    // ---- lane role: col c, batch b (8 real rows), tile-select dup, unit u ----
    const int c   = L & 15;
    const int b   = c & 7;
    const int dup = (c >> 3) & 1;
    const int u   = 8 * w + 4 * dup + (L >> 4);
    // 64 lanes <-> 64 distinct (b,u): exactly one activation per lane.

    // exp2-domain gate params: sigmoid arg -K*a, tanh arg +2K*a (K=log2 e)
    const float K = 1.44269504f;
    float wih[4], bias[4], dscl[4];
#pragma unroll
    for (int g = 0; g < 4; ++g) {
        const float s = (g == 2) ? 2.0f * K : -K;
        wih[g]  = s * W_ih[g * HID + u];
        bias[g] = s * (b_ih[g * HID + u] + b_hh[g * HID + u]);
        dscl[g] = s;
    }

    const float* xrow = &xs[b][0];
    const int koff = (L >> 4) * 8;
    const _Float16* h0r = &hbuf[0][b][0];
    _Float16*       h0w = &hbuf[0][0][0];
    const _Float16* h1r = &hbuf[1][b][0];
    _Float16*       h1w = &hbuf[1][0][0];
    const int widx = b * 72 + u;     // write offset within a buffer
    const f32x4 zero = {0.0f, 0.0f, 0.0f, 0.0f};
    float cst = 0.0f;

    __syncthreads();

    auto step = [&](const _Float16* hin, _Float16* hout, float xt) {
        half8 b0 = *(const half8*)(hin + koff);
        half8 b1 = *(const half8*)(hin + koff + 32);

        f32x4 d0 = __builtin_amdgcn_mfma_f32_16x16x32_f16(af[0][0], b0, zero, 0, 0, 0);
        f32x4 d1 = __builtin_amdgcn_mfma_f32_16x16x32_f16(af[1][0], b0, zero, 0, 0, 0);
        d0 = __builtin_amdgcn_mfma_f32_16x16x32_f16(af[0][1], b1, d0, 0, 0, 0);
        d1 = __builtin_amdgcn_mfma_f32_16x16x32_f16(af[1][1], b1, d1, 0, 0, 0);

        const f32x4 d = dup ? d1 : d0;   // select-of-2: 4 cndmask

        const float ei = exp2_fast(fmaf(d[0], dscl[0], fmaf(xt, wih[0], bias[0])));
        const float ef = exp2_fast(fmaf(d[1], dscl[1], fmaf(xt, wih[1], bias[1])));
        const float eg = exp2_fast(fmaf(d[2], dscl[2], fmaf(xt, wih[2], bias[2])));
        const float eo = exp2_fast(fmaf(d[3], dscl[3], fmaf(xt, wih[3], bias[3])));
        const float gi = rcp_fast(1.0f + ei);                    // sigmoid(i)
        const float gf = rcp_fast(1.0f + ef);                    // sigmoid(f)
        const float gg = fmaf(-2.0f, rcp_fast(1.0f + eg), 1.0f); // tanh(g)
        const float go = rcp_fast(1.0f + eo);                    // sigmoid(o)
        cst = fmaf(gf, cst, gi * gg);
        const float tc = fmaf(-2.0f, rcp_fast(1.0f + exp2_fast(2.0f * K * cst)), 1.0f);
        hout[widx] = (_Float16)(go * tc);  // one write per lane, 64 unique (b,u)
    };

    for (int t = 0; t < TLEN; t += 2) {
        step(h0r, h1w, xrow[t]);
        __syncthreads();
        step(h1r, h0w, xrow[t + 1]);
        __syncthreads();
    }

    // ---- epilogue: wave w reduces batch row w (final h in hbuf[0]) ----
    float pv = (float)hbuf[0][w][L] * W_d[L];
#pragma unroll
    for (int off = 32; off > 0; off >>= 1)
        pv += __shfl_xor(pv, off, 64);
    if (L == 0)
        out[r0 + w] = pv + b_d[0];
}

extern "C" void kernel_launch(void* const* d_in, const int* in_sizes, int n_in,
                              void* d_out, int out_size, void* d_ws, size_t ws_size,
                              hipStream_t stream) {
    const float* x    = (const float*)d_in[0];
    const float* W_ih = (const float*)d_in[1];
    const float* W_hh = (const float*)d_in[2];
    const float* b_ih = (const float*)d_in[3];
    const float* b_hh = (const float*)d_in[4];
    const float* W_d  = (const float*)d_in[5];
    const float* b_d  = (const float*)d_in[6];
    float* out = (float*)d_out;

    dim3 grid(256);    // 2048 / 8 batch rows per block -> 1 block/CU
    dim3 block(512);   // 8 waves = 2/SIMD (the 1-act/lane occupancy floor)
    lstm_mfma6<<<grid, block, 0, stream>>>(x, W_ih, W_hh, b_ih, b_hh, W_d, b_d, out);
}